// Round 10
// baseline (78.218 us; speedup 1.0000x reference)
//
#include <hip/hip_runtime.h>
#include <hip/hip_bf16.h>

// DenseGraphSimpleOpEdgeFlow: out[b,i,f] = sum_j attn[b,i,j,f]*support[b,j,f] + support[b,i,f]
//   support = inputs @ weight  (fp32)
//   attn = mask(sigmoid(op_emb' @ attn_w + attn_b)); diagonal op_emb replaced by self_op_emb,
//   adj' = adj + I; adj'==0 -> 0, adj'==1 (SKIP) -> 1, else sigmoid.
// R10: R1's max-TLP grid (6144 one-tile blocks; highest measured VALUBusy/occupancy of all
// rounds) + the lean math from R7/R8: 49th-K mask-fold (A[j,48]=off_j, B[48,f]=1 ->
// attn = rcp(1+exp2(acc)), 4 ops/elem), bias folded into MFMA C-init, and support stored in
// FRAGMENT LAYOUT S2[b][lg][fpair][mt][r] so sfrag = 12 contiguous dwordx4 loads (R1 paid 48
// scalar global loads/elem-thread here). No G-loop, no flag sync (R9 raced), 2 barriers total.
// Requires ws_size >= 64*96*128*4 = 3,145,728 bytes (S2 scratch, same size as plain support).

#define B_ 64
#define N_ 96
#define F_ 128
#define D_ 48

typedef __attribute__((ext_vector_type(8))) short short8;
typedef __attribute__((ext_vector_type(4))) float f32x4;

#if __has_builtin(__builtin_amdgcn_exp2f)
#define EXP2(x) __builtin_amdgcn_exp2f(x)
#else
#define EXP2(x) exp2f(x)
#endif

// S2 fragment layout: float2 index (((b*4 + lg)*64 + fbp)*6 + mt)*4 + r
__device__ __forceinline__ size_t s2idx(int b, int lg, int fbp, int mt, int r) {
    return ((((size_t)b * 4 + lg) * 64 + fbp) * 6 + mt) * 4 + r;
}

__device__ __forceinline__ unsigned bfbits(float x) {
    union { __hip_bfloat16 h; unsigned short u; } cv;
    cv.h = __float2bfloat16(x);
    return (unsigned)cv.u;
}

// ---------------- Kernel 1: support = inputs @ weight, written in fragment layout ----------------
__global__ __launch_bounds__(256, 4) void support_kernel(
    const float* __restrict__ inputs, const float* __restrict__ weight,
    float2* __restrict__ S2)
{
    __shared__ float in_lds[16 * F_];
    const int tid = threadIdx.x;
    const int row0 = blockIdx.x * 16;
    ((float4*)in_lds)[tid]       = ((const float4*)(inputs + (size_t)row0 * F_))[tid];
    ((float4*)in_lds)[tid + 256] = ((const float4*)(inputs + (size_t)row0 * F_))[tid + 256];
    __syncthreads();
    const int rl = tid >> 4, f0 = (tid & 15) * 8;
    float acc[8] = {0.f,0.f,0.f,0.f,0.f,0.f,0.f,0.f};
    #pragma unroll 4
    for (int k = 0; k < F_; ++k) {
        const float a = in_lds[rl * F_ + k];
        const float4 w0 = *(const float4*)(weight + k * F_ + f0);
        const float4 w1 = *(const float4*)(weight + k * F_ + f0 + 4);
        acc[0] += a * w0.x; acc[1] += a * w0.y; acc[2] += a * w0.z; acc[3] += a * w0.w;
        acc[4] += a * w1.x; acc[5] += a * w1.y; acc[6] += a * w1.z; acc[7] += a * w1.w;
    }
    const int R = row0 + rl;
    const int b = R / N_, j = R - b * N_;
    const int mt = j >> 4, lg = (j >> 2) & 3, r = j & 3;
    #pragma unroll
    for (int q = 0; q < 4; ++q) {
        const int fbp = (f0 >> 1) + q;   // f-pair index
        S2[s2idx(b, lg, fbp, mt, r)] = make_float2(acc[2 * q], acc[2 * q + 1]);
    }
}

// ---------------- Kernel 2: fused attn-GEMM + mask + weighted reduce + residual ----------------
// One block per (b,i); 4 waves; wave w owns f = w*32 + (lane&15)*2 + t.
// MFMA 16x16x32 k-slot fill d = ks*32 + (lane>>4)*8 + e, identical for A and B (physical-k
// permutation cancels). C/D (HW-verified): col = lane&15 (-> f-pair), row = (lane>>4)*4+reg (-> j).
__global__ __launch_bounds__(256, 2) void fused_kernel(
    const float* __restrict__ op_emb,
    const unsigned* __restrict__ adjw,      // raw 32-bit view of adj (int32 or int64)
    const float* __restrict__ attn_w,
    const float* __restrict__ attn_b,
    const float* __restrict__ self_op,
    const float2* __restrict__ S2,
    float* __restrict__ out)
{
    __shared__ __align__(16) unsigned short Atile[N_ * 64];  // 12 KB; d=48 is the mask slot

    const int tid  = threadIdx.x;
    const int lane = tid & 63;
    const int wv   = tid >> 6;      // wave 0..3
    const int lg   = lane >> 4;     // k-slot group / j-subgroup 0..3
    const int lm   = lane & 15;
    const int fb   = wv * 32 + lm * 2;   // f-pair base
    const int fbp  = wv * 16 + lm;       // f-pair index

    const int blk = blockIdx.x;
    const int b   = blk / N_;
    const int i   = blk - b * N_;
    const size_t rb = (size_t)(b * N_ + i) * N_;
    const float* src = op_emb + rb * D_;

    const float kNL2E = -1.44269504088896f;   // -log2(e)

    // --- adj dtype sniff: int64 little-endian has all-zero high words (values 0..4) ---
    const unsigned probe = adjw[2 * lane + 1];
    const bool use32 = __any(probe != 0);

    // ---- staging loads issue first (latency hidden under preamble VALU) ----
    float4 ld[5];
    #pragma unroll
    for (int s = 0; s < 5; ++s) {
        const int w = tid + s * 256;
        if (w < N_ * 12) {
            const int j = w / 12, c = w - 12 * j;
            ld[s] = (j == i) ? *(const float4*)(self_op + c * 4)
                             : *(const float4*)(src + (size_t)j * D_ + c * 4);
        }
    }
    int araw = 0;
    if (tid < N_) {
        const size_t idx = rb + tid;
        araw = use32 ? (int)adjw[idx] : (int)adjw[2 * idx];
        araw += (tid == i) ? 1 : 0;
    }

    // --- B fragments (attn_w pre-scaled by -log2e; d==48 -> 1.0) + bias ---
    short8 bfrag[2][2];     // [t][ks]
    float  bbias[2];
    {
        const float2 bb = *(const float2*)(attn_b + fb);
        bbias[0] = bb.x * kNL2E;
        bbias[1] = bb.y * kNL2E;
        #pragma unroll
        for (int ks = 0; ks < 2; ++ks) {
            short8 v0, v1;
            #pragma unroll
            for (int e = 0; e < 8; ++e) {
                const int d = ks * 32 + lg * 8 + e;
                if (d < D_) {
                    const float2 w = *(const float2*)(attn_w + d * F_ + fb);
                    v0[e] = (short)bfbits(w.x * kNL2E);
                    v1[e] = (short)bfbits(w.y * kNL2E);
                } else {
                    const unsigned one = (d == D_) ? bfbits(1.0f) : 0u;  // mask-slot weight
                    v0[e] = (short)one;
                    v1[e] = (short)one;
                }
            }
            bfrag[0][ks] = v0;
            bfrag[1][ks] = v1;
        }
    }

    // --- support fragments: 24 consecutive float2 = 12 dwordx4 from the frag layout ---
    float2 sfrag[6][4];
    {
        const float4* sp = (const float4*)(S2 + s2idx(b, lg, fbp, 0, 0));
        #pragma unroll
        for (int q = 0; q < 12; ++q) {
            const float4 v = sp[q];
            sfrag[(2 * q) / 4][(2 * q) & 3]     = make_float2(v.x, v.y);
            sfrag[(2 * q + 1) / 4][(2 * q + 1) & 3] = make_float2(v.z, v.w);
        }
    }

    // --- zero the k-pad d in [50,64): bytes 100..127 per row ---
    for (int v = tid; v < N_ * 7; v += 256) {
        const int j = v / 7, q = v - 7 * j;
        const int byte = j * 128 + ((100 + q * 4) ^ ((j & 7) << 4));
        *(unsigned*)((char*)Atile + byte) = 0u;
    }

    // ---- stage: bf16 LDS (XOR-swizzled); d48 <- off_j mask slot ----
    #pragma unroll
    for (int s = 0; s < 5; ++s) {
        const int w = tid + s * 256;
        if (w < N_ * 12) {
            const int j = w / 12, c = w - 12 * j;
            const int byte = j * 128 + ((c * 8) ^ ((j & 7) << 4));
            *(uint2*)((char*)Atile + byte) =
                make_uint2(bfbits(ld[s].x) | (bfbits(ld[s].y) << 16),
                           bfbits(ld[s].z) | (bfbits(ld[s].w) << 16));
        }
    }
    if (tid < N_) {
        // off: a'==0 -> +126 (attn 0 via exp2 saturation), a'==1 -> -126 (attn 1), else 0
        const float off = (araw == 0) ? 126.f : ((araw == 1) ? -126.f : 0.f);
        const int byte = tid * 128 + (96 ^ ((tid & 7) << 4));
        *(unsigned*)((char*)Atile + byte) = bfbits(off);
    }
    __syncthreads();

    // ---- compute: 6 j-slabs, epilogue interleaved per-slab (acc stays at 8 regs) ----
    float osum0 = 0.f, osum1 = 0.f;
    #pragma unroll
    for (int mt = 0; mt < 6; ++mt) {
        const int jr  = mt * 16 + lm;
        const int swz = (lm & 7) << 4;
        const char* base = (const char*)Atile + jr * 128;
        const short8 a0 = *(const short8*)(base + (( 0 + lg * 16) ^ swz));
        const short8 a1 = *(const short8*)(base + ((64 + lg * 16) ^ swz));
        f32x4 c0 = (f32x4){bbias[0], bbias[0], bbias[0], bbias[0]};
        f32x4 c1 = (f32x4){bbias[1], bbias[1], bbias[1], bbias[1]};
        c0 = __builtin_amdgcn_mfma_f32_16x16x32_bf16(a0, bfrag[0][0], c0, 0, 0, 0);
        c0 = __builtin_amdgcn_mfma_f32_16x16x32_bf16(a1, bfrag[0][1], c0, 0, 0, 0);
        c1 = __builtin_amdgcn_mfma_f32_16x16x32_bf16(a0, bfrag[1][0], c1, 0, 0, 0);
        c1 = __builtin_amdgcn_mfma_f32_16x16x32_bf16(a1, bfrag[1][1], c1, 0, 0, 0);
        // attn = rcp(1 + exp2(acc)); saturation encodes the mask (acc includes off_j)
        #pragma unroll
        for (int r = 0; r < 4; ++r) {
            const float s0 = __builtin_amdgcn_rcpf(1.f + EXP2(c0[r]));
            const float s1 = __builtin_amdgcn_rcpf(1.f + EXP2(c1[r]));
            osum0 = __builtin_fmaf(s0, sfrag[mt][r].x, osum0);
            osum1 = __builtin_fmaf(s1, sfrag[mt][r].y, osum1);
        }
    }

    // ---- reduce over the 4 lg j-subsets; lanes 0..15 add residual and store ----
    osum0 += __shfl_xor(osum0, 16);
    osum0 += __shfl_xor(osum0, 32);
    osum1 += __shfl_xor(osum1, 16);
    osum1 += __shfl_xor(osum1, 32);
    if (lg == 0) {
        const float2 sr = S2[s2idx(b, (i >> 2) & 3, fbp, i >> 4, i & 3)];
        float2 o;
        o.x = osum0 + sr.x;
        o.y = osum1 + sr.y;
        *(float2*)(out + (size_t)(b * N_ + i) * F_ + fb) = o;
    }
}

extern "C" void kernel_launch(void* const* d_in, const int* in_sizes, int n_in,
                              void* d_out, int out_size, void* d_ws, size_t ws_size,
                              hipStream_t stream) {
    const float*    inputs  = (const float*)d_in[0];
    const unsigned* adjw    = (const unsigned*)d_in[1];
    const float*    op_emb  = (const float*)d_in[2];
    const float*    weight  = (const float*)d_in[3];
    const float*    attn_w  = (const float*)d_in[4];
    const float*    attn_b  = (const float*)d_in[5];
    const float*    self_op = (const float*)d_in[6];
    float* out = (float*)d_out;
    float2* S2 = (float2*)d_ws;  // fragment-layout support, 3,145,728 bytes

    support_kernel<<<(B_ * N_) / 16, 256, 0, stream>>>(inputs, weight, S2);
    fused_kernel<<<B_ * N_, 256, 0, stream>>>(op_emb, adjw, attn_w, attn_b, self_op,
                                              S2, out);
}